// Round 11
// baseline (819.623 us; speedup 1.0000x reference)
//
#include <hip/hip_runtime.h>
#include <stdint.h>
#include <stddef.h>

#define Bn    16
#define Nn    10000
#define En    320000
#define CIN   32
#define COUTn 64
#define CCn   96
#define WROWU 768           // uints per full node row (16 batches * 96ch / 2)
#define RHU   512           // uints per rh-only node row (16 * 64 / 2)
#define MROWS 160000        // Nn * Bn
#define GDEG  (En / 256)           // 1250 degree blocks
#define GX0   (Nn * WROWU / 256)   // 30000 blocks for x0 build

typedef __attribute__((ext_vector_type(8))) short short8;   // 8 bf16 = 4 VGPRs
typedef __attribute__((ext_vector_type(4))) float f32x4;
typedef __attribute__((ext_vector_type(2))) float f32x2;
typedef __attribute__((ext_vector_type(4))) unsigned int uint4v;

// ---------------- direct global->LDS (gfx950) ----------------
#if __has_builtin(__builtin_amdgcn_global_load_lds)
#define HAVE_GLL 1
typedef __attribute__((address_space(3))) unsigned char lds_u8;
typedef __attribute__((address_space(1))) const unsigned char glb_u8;
// HW semantics: LDS dest = wave-uniform base + lane*16; global src is per-lane.
__device__ __forceinline__ void gll16(const void* g, void* l) {
  __builtin_amdgcn_global_load_lds((glb_u8*)g, (lds_u8*)l, 16, 0, 0);
}
#else
#define HAVE_GLL 0
#endif

// ---------------- bf16 helpers ----------------
__device__ __forceinline__ float bflo(unsigned int p) { return __uint_as_float(p << 16); }
__device__ __forceinline__ float bfhi(unsigned int p) { return __uint_as_float(p & 0xffff0000u); }
__device__ __forceinline__ float bf2f(unsigned short u) { return __uint_as_float(((unsigned int)u) << 16); }
__device__ __forceinline__ unsigned int f2bfbits(float f) {
  unsigned int x = __float_as_uint(f);
  return (x + 0x7fffu + ((x >> 16) & 1u)) >> 16;
}
__device__ __forceinline__ unsigned int pack2(float lo, float hi) {
  return f2bfbits(lo) | (f2bfbits(hi) << 16);
}

// ---------------- edge_index dtype detection (parallel, 64 lanes) ----------------
__global__ void detect_idx(const int* __restrict__ idx, int* __restrict__ flag) {
  int t = threadIdx.x;                 // 64 threads
  int v = idx[1 + 2 * t];              // odd positions 1..127
  unsigned long long bal = __ballot(v != 0);
  if (t == 0) flag[0] = (bal == 0ULL) ? 1 : 0;
}

__device__ __forceinline__ int gidx(const int* __restrict__ p, int i, int is64) {
  return is64 ? p[2 * (long long)i] : p[i];
}

// ---------------- fused: degree/CSR counts + X0 build + weight prep ----------------
// blocks [0,GDEG): degrees; [GDEG,GDEG+GX0): X0 rows; [GDEG+GX0,+240): weights
// (transposed bf16, W0 folded as W0 - W3 - W4).
__global__ void deg_x0_wt(const int* __restrict__ idx, const float* __restrict__ w,
                          float* __restrict__ deg_f, float* __restrict__ deg_b,
                          int* __restrict__ cnt_f, int* __restrict__ cnt_b,
                          const int* __restrict__ flag,
                          const float* __restrict__ x, const float* __restrict__ h,
                          unsigned int* __restrict__ X0,
                          const float* __restrict__ ru_p, const float* __restrict__ c_p,
                          unsigned short* __restrict__ Wt1, unsigned short* __restrict__ Wt2) {
  int blk = blockIdx.x;
  if (blk < GDEG) {
    int e = blk * 256 + threadIdx.x;
    int is64 = flag[0];
    if (e < En) {
      int s = gidx(idx, e, is64);
      int d = gidx(idx, En + e, is64);
      float we = w[e];
      atomicAdd(&deg_f[s], we);
      atomicAdd(&deg_b[d], we);
      atomicAdd(&cnt_f[d], 1);
      atomicAdd(&cnt_b[s], 1);
    }
  } else if (blk < GDEG + GX0) {
    long long p = (long long)(blk - GDEG) * 256 + threadIdx.x;
    int node = (int)(p / WROWU);
    int rem = (int)(p % WROWU);
    int b = rem / 48;
    int ci = (rem % 48) * 2;
    float lo, hi;
    if (ci < CIN) {
      const float* s = x + ((size_t)b * Nn + node) * CIN + ci;
      lo = s[0]; hi = s[1];
    } else {
      const float* s = h + ((size_t)b * Nn + node) * COUTn + (ci - CIN);
      lo = s[0]; hi = s[1];
    }
    X0[p] = pack2(lo, hi);
  } else {
    int i = (blk - GDEG - GX0) * 256 + threadIdx.x;
    if (i < 128 * 480) {
      int n = i / 480, k = i % 480;
      int t = k / 96, kk = k % 96;
      float v;
      if (t == 0) v = ru_p[(kk * 5 + 0) * 128 + n] - ru_p[(kk * 5 + 3) * 128 + n] - ru_p[(kk * 5 + 4) * 128 + n];
      else        v = ru_p[(kk * 5 + t) * 128 + n];
      Wt1[i] = (unsigned short)f2bfbits(v);
    }
    if (i < 64 * 480) {
      int n = i / 480, k = i % 480;
      int t = k / 96, kk = k % 96;
      float v;
      if (t == 0) v = c_p[(kk * 5 + 0) * 64 + n] - c_p[(kk * 5 + 3) * 64 + n] - c_p[(kk * 5 + 4) * 64 + n];
      else        v = c_p[(kk * 5 + t) * 64 + n];
      Wt2[i] = (unsigned short)f2bfbits(v);
    }
  }
}

// ---------------- exclusive scan (thread-coarsened: 40 elems/thread) ----------------
__global__ void exscan_two(const int* __restrict__ cnt_f, const int* __restrict__ cnt_b,
                           int* __restrict__ rp_f, int* __restrict__ rp_b,
                           int* __restrict__ cur_f, int* __restrict__ cur_b, int n) {
  const int* cnt = (blockIdx.x == 0) ? cnt_f : cnt_b;
  int* rp  = (blockIdx.x == 0) ? rp_f  : rp_b;
  int* cur = (blockIdx.x == 0) ? cur_f : cur_b;
  __shared__ int sh[256];
  int t = threadIdx.x;
  int CH = (n + 255) / 256;
  int s0 = t * CH;
  int s1 = s0 + CH; if (s1 > n) s1 = n;
  int s = 0;
  for (int i = s0; i < s1; ++i) s += cnt[i];
  sh[t] = s;
  __syncthreads();
  for (int off = 1; off < 256; off <<= 1) {
    int x = (t >= off) ? sh[t - off] : 0;
    __syncthreads();
    sh[t] += x;
    __syncthreads();
  }
  int run = sh[t] - s;                 // exclusive prefix for this thread's chunk
  for (int i = s0; i < s1; ++i) {
    rp[i] = run; cur[i] = run; run += cnt[i];
  }
  if (t == 255) rp[n] = sh[255];
}

// ---------------- CSR fill: packed (col, w) uint2 ----------------
__global__ void fill_csr(const int* __restrict__ idx, const float* __restrict__ w,
                         const float* __restrict__ deg_f, const float* __restrict__ deg_b,
                         int* __restrict__ cur_f, int* __restrict__ cur_b,
                         uint2* __restrict__ cwf, uint2* __restrict__ cwb,
                         const int* __restrict__ flag) {
  int e = blockIdx.x * 256 + threadIdx.x;
  int is64 = flag[0];
  if (e < En) {
    int s = gidx(idx, e, is64);
    int d = gidx(idx, En + e, is64);
    float we = w[e];
    int pf = atomicAdd(&cur_f[d], 1);
    cwf[pf] = make_uint2((unsigned int)s, __float_as_uint(we / deg_f[s]));
    int pb = atomicAdd(&cur_b[s], 1);
    cwb[pb] = make_uint2((unsigned int)d, __float_as_uint(we / deg_b[d]));
  }
}

// ---------------- XCD-sliced propagation (structure FROZEN: see R1-R10 notes) ----
// slice = blockIdx & 7 -> per-XCD L2-resident node slice (FETCH 627->175 MB).
// EPW edges/gather (R7 -25%); wave-uniform scalar descriptors (R3/R5 lesson);
// umul24 32-bit addressing + packed f32 (R8). L1/L2 line-rate bound floor.
template<int RU4, int ACT, int EPW>
__device__ __forceinline__ void prop_rowX(const uint4v* __restrict__ in,
                                          uint4v* __restrict__ out,
                                          const int* __restrict__ rp,
                                          const uint2* __restrict__ cw,
                                          int row, int slice, int lane, float alpha) {
  constexpr int GSZ = 64 / EPW;
  constexpr unsigned RB = (unsigned)RU4 * 16u;   // row bytes (3072 / 2048)
  int grp = (EPW == 2) ? (lane >> 5) : (lane >> 4);
  int lg = lane & (GSZ - 1);
  int lgc = (lg < ACT) ? lg : 0;       // pad lanes duplicate lane 0's line (coalesced, free)
  unsigned laneByte = (unsigned)(slice * ACT + lgc) * 16u;
  const char* __restrict__ inB = (const char*)in;
  int jb = __builtin_amdgcn_readfirstlane(rp[row]);
  int je = __builtin_amdgcn_readfirstlane(rp[row + 1]);
  int len = je - jb;

  f32x2 a0 = {0.f, 0.f}, a1 = {0.f, 0.f}, a2 = {0.f, 0.f}, a3 = {0.f, 0.f};

  constexpr int STEP = 4 * EPW;        // 4 gather instrs in flight per wave
  int i = jb;
  int eM = jb + (len / STEP) * STEP;
  for (; i < eM; i += STEP) {
    #pragma unroll
    for (int k = 0; k < 4; ++k) {
      unsigned int col; float w;
      {
        uint2 e0 = cw[i + k * EPW + 0];
        uint2 e1 = cw[i + k * EPW + 1];
        col = (grp & 1) ? e1.x : e0.x;
        w = __uint_as_float((grp & 1) ? e1.y : e0.y);
        if (EPW == 4) {
          uint2 e2 = cw[i + k * EPW + 2];
          uint2 e3 = cw[i + k * EPW + 3];
          unsigned int colB = (grp & 1) ? e3.x : e2.x;
          float wB = __uint_as_float((grp & 1) ? e3.y : e2.y);
          col = (grp & 2) ? colB : col;
          w = (grp & 2) ? wB : w;
        }
      }
      unsigned off = __umul24(col, RB) + laneByte;     // u32, < 31 MB: safe
      uint4v q = *(const uint4v*)(inB + off);
      f32x2 wv = {w, w};
      f32x2 v0 = {bflo(q.x), bfhi(q.x)};
      f32x2 v1 = {bflo(q.y), bfhi(q.y)};
      f32x2 v2 = {bflo(q.z), bfhi(q.z)};
      f32x2 v3 = {bflo(q.w), bfhi(q.w)};
      a0 += wv * v0; a1 += wv * v1; a2 += wv * v2; a3 += wv * v3;
    }
  }
  // masked tail, EPW edges per step (clamped uniform descriptor indices)
  for (; i < je; i += EPW) {
    unsigned int col; float w;
    {
      uint2 e0 = cw[i + 0];
      uint2 e1 = cw[(i + 1 < je) ? i + 1 : i];
      col = (grp & 1) ? e1.x : e0.x;
      w = __uint_as_float((grp & 1) ? e1.y : e0.y);
      if (EPW == 4) {
        uint2 e2 = cw[(i + 2 < je) ? i + 2 : i];
        uint2 e3 = cw[(i + 3 < je) ? i + 3 : i];
        unsigned int colB = (grp & 1) ? e3.x : e2.x;
        float wB = __uint_as_float((grp & 1) ? e3.y : e2.y);
        col = (grp & 2) ? colB : col;
        w = (grp & 2) ? wB : w;
      }
    }
    if (i + grp >= je) w = 0.f;        // invalid lanes contribute 0 (clamped addr is safe)
    unsigned off = __umul24(col, RB) + laneByte;
    uint4v q = *(const uint4v*)(inB + off);
    f32x2 wv = {w, w};
    f32x2 v0 = {bflo(q.x), bfhi(q.x)};
    f32x2 v1 = {bflo(q.y), bfhi(q.y)};
    f32x2 v2 = {bflo(q.z), bfhi(q.z)};
    f32x2 v3 = {bflo(q.w), bfhi(q.w)};
    a0 += wv * v0; a1 += wv * v1; a2 += wv * v2; a3 += wv * v3;
  }

  // cross-group reduce
  if (EPW == 4) {
    a0.x += __shfl_xor(a0.x, 16); a0.y += __shfl_xor(a0.y, 16);
    a1.x += __shfl_xor(a1.x, 16); a1.y += __shfl_xor(a1.y, 16);
    a2.x += __shfl_xor(a2.x, 16); a2.y += __shfl_xor(a2.y, 16);
    a3.x += __shfl_xor(a3.x, 16); a3.y += __shfl_xor(a3.y, 16);
  }
  a0.x += __shfl_xor(a0.x, 32); a0.y += __shfl_xor(a0.y, 32);
  a1.x += __shfl_xor(a1.x, 32); a1.y += __shfl_xor(a1.y, 32);
  a2.x += __shfl_xor(a2.x, 32); a2.y += __shfl_xor(a2.y, 32);
  a3.x += __shfl_xor(a3.x, 32); a3.y += __shfl_xor(a3.y, 32);

  if (grp == 0 && lg < ACT) {
    uint4v o;
    o.x = pack2(alpha * a0.x, alpha * a0.y);
    o.y = pack2(alpha * a1.x, alpha * a1.y);
    o.z = pack2(alpha * a2.x, alpha * a2.y);
    o.w = pack2(alpha * a3.x, alpha * a3.y);
    out[(size_t)row * RU4 + slice * ACT + lg] = o;
  }
}

template<int RU4, int ACT, int EPW>
__launch_bounds__(256)
__global__ void prop_dualX(const uint4v* __restrict__ in,
                           uint4v* __restrict__ outF, uint4v* __restrict__ outB,
                           const int* __restrict__ rp_f, const uint2* __restrict__ cwf,
                           const int* __restrict__ rp_b, const uint2* __restrict__ cwb) {
  int lane = threadIdx.x & 63;
  int wave = threadIdx.x >> 6;
  int slice = blockIdx.x & 7;
  int row = ((blockIdx.x >> 3) << 2) + wave;
  prop_rowX<RU4, ACT, EPW>(in, outF, rp_f, cwf, row, slice, lane, 1.f);
  prop_rowX<RU4, ACT, EPW>(in, outB, rp_b, cwb, row, slice, lane, 1.f);
}

template<int RU4, int ACT, int EPW>
__launch_bounds__(256)
__global__ void prop_ckX(const uint4v* __restrict__ in, uint4v* __restrict__ out,
                         const int* __restrict__ rp, const uint2* __restrict__ cw,
                         float alpha) {
  int lane = threadIdx.x & 63;
  int wave = threadIdx.x >> 6;
  int slice = blockIdx.x & 7;
  int row = ((blockIdx.x >> 3) << 2) + wave;
  prop_rowX<RU4, ACT, EPW>(in, out, rp, cw, row, slice, lane, alpha);
}

// ---------------- MFMA multi-term GEMM (LDS A+B; for solo dispatches) ----------------
// C[128 x NT] per block; 4 waves, each 32 x NT. K = nterms*96.
// LINEAR LDS tiles (row stride 192 B -> ds_read_b128 at the bank floor).
// MODE 0: conv1 epilogue sigmoid + r*h + u-store
// MODE 1: outp = bias + acc (f32, batch-major)
// MODE 2: cp = outp + acc; c=tanh(tanh(cp)); u from U_in; outp = u*h + (1-u)*c
// MODE 4: v += Pbuf[row*128+col] (partial from passA), then MODE-0 epilogue
struct Msrc {
  const uint4* xs[5];
  const uint4* rh[5];
};

template<int NT, int MODE>
__device__ __forceinline__ void gemm_body(int blk, Msrc g, int nterms, int t0,
                          const unsigned short* __restrict__ Wt,
                          const float* __restrict__ bias,
                          float* __restrict__ outp,
                          unsigned short* __restrict__ rh0_s,
                          unsigned short* __restrict__ U_out,
                          const unsigned short* __restrict__ U_in,
                          const float* __restrict__ hglob,
                          const float* __restrict__ Pbuf) {
  constexpr int NJ = NT / 16;
  __shared__ __align__(16) unsigned short As[128 * 96];
  __shared__ __align__(16) unsigned short Bs[NT * 96];

  int m0 = blk * 128;
  int tid = threadIdx.x;
  int wave = tid >> 6;
  int lane = tid & 63;
  int quad = lane >> 4;
  int lm = lane & 15;
  int wm = wave * 32;
  int nodeBase = m0 >> 4;

  f32x4 acc[2][NJ];
  #pragma unroll
  for (int i = 0; i < 2; ++i)
    #pragma unroll
    for (int j = 0; j < NJ; ++j) acc[i][j] = (f32x4){0.f, 0.f, 0.f, 0.f};

  for (int t = 0; t < nterms; ++t) {
    const uint4* xs4 = g.xs[t];
    const uint4* rh4 = g.rh[t];
    if (rh4 == nullptr) {
      const uint4* src = xs4 + (size_t)m0 * 12;
#if HAVE_GLL
      #pragma unroll
      for (int it = 0; it < 6; ++it) {
        int q = tid + it * 256;
        gll16(src + q, (char*)As + (q & ~63) * 16);
      }
#else
      #pragma unroll
      for (int it = 0; it < 6; ++it) {
        int q = tid + it * 256;
        uint4 v = src[q];
        *(uint4*)&As[q * 8] = v;
      }
#endif
    } else {
      #pragma unroll
      for (int it = 0; it < 6; ++it) {
        int q = tid + it * 256;
        int row = q / 12, slot = q % 12;
        int node = nodeBase + (row >> 4);
        int b = row & 15;
        uint4 v;
        if (slot < 4) v = xs4[(size_t)node * 192 + b * 12 + slot];
        else          v = rh4[(size_t)node * 128 + b * 8 + (slot - 4)];
        *(uint4*)&As[q * 8] = v;       // ci0 == slot*8 -> linear position q*16B
      }
    }
#if HAVE_GLL
    #pragma unroll
    for (int it = 0; it < NT * 12 / 256; ++it) {
      int q = tid + it * 256;
      int n = q / 12, slot = q % 12;
      gll16(Wt + (size_t)n * 480 + (t0 + t) * 96 + slot * 8, (char*)Bs + (q & ~63) * 16);
    }
#else
    for (int q = tid; q < NT * 12; q += 256) {
      int n = q / 12, slot = q % 12;
      uint4 v = *(const uint4*)(Wt + (size_t)n * 480 + (t0 + t) * 96 + slot * 8);
      *(uint4*)&Bs[q * 8] = v;
    }
#endif
    __syncthreads();

    #pragma unroll
    for (int k32 = 0; k32 < 3; ++k32) {
      int kb = k32 * 32 + quad * 8;
      short8 a0 = *(const short8*)&As[(wm + lm) * 96 + kb];
      short8 a1 = *(const short8*)&As[(wm + 16 + lm) * 96 + kb];
      #pragma unroll
      for (int j = 0; j < NJ; ++j) {
        short8 bf = *(const short8*)&Bs[(j * 16 + lm) * 96 + kb];
        acc[0][j] = __builtin_amdgcn_mfma_f32_16x16x32_bf16(a0, bf, acc[0][j], 0, 0, 0);
        acc[1][j] = __builtin_amdgcn_mfma_f32_16x16x32_bf16(a1, bf, acc[1][j], 0, 0, 0);
      }
    }
    __syncthreads();
  }

  #pragma unroll
  for (int i = 0; i < 2; ++i) {
    #pragma unroll
    for (int j = 0; j < NJ; ++j) {
      int col = j * 16 + lm;
      #pragma unroll
      for (int r = 0; r < 4; ++r) {
        int row = m0 + wm + i * 16 + quad * 4 + r;
        int node = row >> 4, b = row & 15;
        float v = acc[i][j][r];
        if (MODE == 0 || MODE == 4) {
          if (MODE == 4) v += Pbuf[(size_t)row * 128 + col];
          float s = 1.f / (1.f + expf(-(bias[col] + v)));
          if (col < COUTn) {
            float hv = hglob[((size_t)b * Nn + node) * COUTn + col];
            rh0_s[(size_t)row * 64 + col] = (unsigned short)f2bfbits(s * hv);
          } else {
            U_out[(size_t)row * 64 + (col - COUTn)] = (unsigned short)f2bfbits(s);
          }
        } else if (MODE == 1) {
          outp[((size_t)b * Nn + node) * COUTn + col] = bias[col] + v;
        } else {
          size_t oa = ((size_t)b * Nn + node) * COUTn + col;
          float cp = outp[oa] + v;
          float c = tanhf(tanhf(cp));
          float u = bf2f(U_in[(size_t)row * 64 + col]);
          outp[oa] = u * hglob[oa] + (1.f - u) * c;
        }
      }
    }
  }
}

template<int NT, int MODE>
__launch_bounds__(256)
__global__ void gemm_mfma(Msrc g, int nterms, int t0,
                          const unsigned short* __restrict__ Wt,
                          const float* __restrict__ bias,
                          float* __restrict__ outp,
                          unsigned short* __restrict__ rh0_s,
                          unsigned short* __restrict__ U_out,
                          const unsigned short* __restrict__ U_in,
                          const float* __restrict__ hglob,
                          const float* __restrict__ Pbuf) {
  gemm_body<NT, MODE>(blockIdx.x, g, nterms, t0, Wt, bias, outp, rh0_s, U_out, U_in, hglob, Pbuf);
}

// ---------------- register-A GEMM (for fused dispatches: LDS = Bs only) ----------
// A fragments loaded per-lane straight from global: same fragment addressing as
// the LDS path (A[m=lane&15][k=quad*8+..]); per-block A tile = 24.6 KB -> L1-
// resident, each 16B read exactly once. Cuts fused-kernel LDS 49->24.6 KB
// (NT=128) / 37->12.3 KB (NT=64), restoring ck-block occupancy.
// MODE 3: Pbuf[row*128+col] = acc (conv1 passA partial, no bias)
// MODE 1: outp = bias + acc (batch-major; conv2 passA)
template<int NT, int MODE>
__device__ __forceinline__ void gemm_regA(int blk, Msrc g, int nterms, int t0,
                          const unsigned short* __restrict__ Wt,
                          const float* __restrict__ bias,
                          float* __restrict__ outp) {
  constexpr int NJ = NT / 16;
  __shared__ __align__(16) unsigned short Bs[NT * 96];
  int m0 = blk * 128;
  int tid = threadIdx.x;
  int wave = tid >> 6;
  int lane = tid & 63;
  int quad = lane >> 4;
  int lm = lane & 15;
  int wm = wave * 32;
  int r0 = m0 + wm + lm, r1 = r0 + 16;

  f32x4 acc[2][NJ];
  #pragma unroll
  for (int i = 0; i < 2; ++i)
    #pragma unroll
    for (int j = 0; j < NJ; ++j) acc[i][j] = (f32x4){0.f, 0.f, 0.f, 0.f};

  for (int t = 0; t < nterms; ++t) {
    const uint4* xs4 = g.xs[t];
    const uint4* rh4 = g.rh[t];
#if HAVE_GLL
    #pragma unroll
    for (int it = 0; it < NT * 12 / 256; ++it) {
      int q = tid + it * 256;
      int n = q / 12, slot = q % 12;
      gll16(Wt + (size_t)n * 480 + (t0 + t) * 96 + slot * 8, (char*)Bs + (q & ~63) * 16);
    }
#else
    for (int q = tid; q < NT * 12; q += 256) {
      int n = q / 12, slot = q % 12;
      *(uint4*)&Bs[q * 8] = *(const uint4*)(Wt + (size_t)n * 480 + (t0 + t) * 96 + slot * 8);
    }
#endif
    __syncthreads();

    #pragma unroll
    for (int k32 = 0; k32 < 3; ++k32) {
      int kb = k32 * 32 + quad * 8;
      int slot = k32 * 4 + quad;                 // kb/8, in uint4 units
      uint4 ar0, ar1;
      if (rh4 == nullptr) {
        ar0 = xs4[(size_t)r0 * 12 + slot];
        ar1 = xs4[(size_t)r1 * 12 + slot];
      } else if (k32 == 0) {                     // shorts 0-31 = x part
        ar0 = xs4[(size_t)(r0 >> 4) * 192 + (r0 & 15) * 12 + slot];
        ar1 = xs4[(size_t)(r1 >> 4) * 192 + (r1 & 15) * 12 + slot];
      } else {                                   // shorts 32-95 = rh part
        ar0 = rh4[(size_t)(r0 >> 4) * 128 + (r0 & 15) * 8 + (slot - 4)];
        ar1 = rh4[(size_t)(r1 >> 4) * 128 + (r1 & 15) * 8 + (slot - 4)];
      }
      short8 a0 = *(const short8*)&ar0;
      short8 a1 = *(const short8*)&ar1;
      #pragma unroll
      for (int j = 0; j < NJ; ++j) {
        short8 bf = *(const short8*)&Bs[(j * 16 + lm) * 96 + kb];
        acc[0][j] = __builtin_amdgcn_mfma_f32_16x16x32_bf16(a0, bf, acc[0][j], 0, 0, 0);
        acc[1][j] = __builtin_amdgcn_mfma_f32_16x16x32_bf16(a1, bf, acc[1][j], 0, 0, 0);
      }
    }
    __syncthreads();
  }

  #pragma unroll
  for (int i = 0; i < 2; ++i) {
    #pragma unroll
    for (int j = 0; j < NJ; ++j) {
      int col = j * 16 + lm;
      #pragma unroll
      for (int r = 0; r < 4; ++r) {
        int row = m0 + wm + i * 16 + quad * 4 + r;
        float v = acc[i][j][r];
        if (MODE == 3) {
          outp[(size_t)row * 128 + col] = v;
        } else {  // MODE 1
          int node = row >> 4, b = row & 15;
          outp[((size_t)b * Nn + node) * COUTn + col] = bias[col] + v;
        }
      }
    }
  }
}

// ---------------- fused: conv1 gemm passA (terms 0-2 -> Pbuf) + conv1 ck F/B ----
// [0,1256): gemm (1250 active); [1256,21256): ckF T1f->T2f; [21256,41256): ckB.
// Bases %8==0 keep slice=b2&7 XCD-consistent. Hazard-free: gemm reads
// A0/T1f/T1b (read-only here), writes Pbuf; cks write T2f/T2b.
__launch_bounds__(256)
__global__ void fused_g1a(Msrc g, const unsigned short* __restrict__ Wt,
                          float* __restrict__ Pbuf,
                          const uint4v* __restrict__ inF, uint4v* __restrict__ outF,
                          const int* __restrict__ rp_f, const uint2* __restrict__ cwf,
                          const uint4v* __restrict__ inB, uint4v* __restrict__ outB,
                          const int* __restrict__ rp_b, const uint2* __restrict__ cwb) {
  int b = blockIdx.x;
  if (b < 1256) {
    if (b < 1250)
      gemm_regA<128, 3>(b, g, 3, 0, Wt, nullptr, Pbuf);
    return;
  }
  int lane = threadIdx.x & 63;
  int wave = threadIdx.x >> 6;
  if (b < 21256) {
    int b2 = b - 1256;
    prop_rowX<192, 24, 2>(inF, outF, rp_f, cwf, ((b2 >> 3) << 2) + wave, b2 & 7, lane, 2.f);
  } else {
    int b2 = b - 21256;
    prop_rowX<192, 24, 2>(inB, outB, rp_b, cwb, ((b2 >> 3) << 2) + wave, b2 & 7, lane, 2.f);
  }
}

// ---------------- fused: conv2 gemm passA (MODE 1) + conv2 ck F/B (regA) -------
__launch_bounds__(256)
__global__ void fused_g2a(Msrc g, const unsigned short* __restrict__ Wt,
                          const float* __restrict__ bias, float* __restrict__ outp,
                          const uint4v* __restrict__ inF, uint4v* __restrict__ outF,
                          const int* __restrict__ rp_f, const uint2* __restrict__ cwf,
                          const uint4v* __restrict__ inB, uint4v* __restrict__ outB,
                          const int* __restrict__ rp_b, const uint2* __restrict__ cwb) {
  int b = blockIdx.x;
  if (b < 1256) {
    if (b < 1250)
      gemm_regA<64, 1>(b, g, 3, 0, Wt, bias, outp);
    return;
  }
  int lane = threadIdx.x & 63;
  int wave = threadIdx.x >> 6;
  if (b < 21256) {
    int b2 = b - 1256;
    prop_rowX<128, 16, 4>(inF, outF, rp_f, cwf, ((b2 >> 3) << 2) + wave, b2 & 7, lane, 2.f);
  } else {
    int b2 = b - 21256;
    prop_rowX<128, 16, 4>(inB, outB, rp_b, cwb, ((b2 >> 3) << 2) + wave, b2 & 7, lane, 2.f);
  }
}

// ---------------- host ----------------
extern "C" void kernel_launch(void* const* d_in, const int* in_sizes, int n_in,
                              void* d_out, int out_size, void* d_ws, size_t ws_size,
                              hipStream_t stream) {
  const float* x   = (const float*)d_in[0];
  const float* h   = (const float*)d_in[1];
  const int*   idx = (const int*)d_in[2];
  const float* ew  = (const float*)d_in[3];
  const float* ru_param = (const float*)d_in[4];
  const float* ru_bias  = (const float*)d_in[5];
  const float* c_param  = (const float*)d_in[6];
  const float* c_bias   = (const float*)d_in[7];
  float* outp = (float*)d_out;
  (void)in_sizes; (void)n_in; (void)out_size;

  char* ws = (char*)d_ws;
  size_t off = 0;
  auto alloc = [&](size_t bytes) -> char* {
    char* p = ws + off;
    off += (bytes + 255) & ~(size_t)255;
    return p;
  };

  float* deg_f = (float*)alloc(40960);
  float* deg_b = (float*)alloc(40960);
  int*   cnt_f = (int*)alloc(40960);
  int*   cnt_b = (int*)alloc(40960);
  int*   rp_f  = (int*)alloc((Nn + 1) * sizeof(int));
  int*   rp_b  = (int*)alloc((Nn + 1) * sizeof(int));
  int*   cur_f = (int*)alloc(Nn * sizeof(int));
  int*   cur_b = (int*)alloc(Nn * sizeof(int));
  int*   flag  = (int*)alloc(256);
  uint2* cwf   = (uint2*)alloc((size_t)En * 8);
  uint2* cwb   = (uint2*)alloc((size_t)En * 8);
  unsigned short* Wt1 = (unsigned short*)alloc(128 * 480 * 2);
  unsigned short* Wt2 = (unsigned short*)alloc(64 * 480 * 2);

  unsigned int* A0   = (unsigned int*)alloc((size_t)Nn * WROWU * 4);
  unsigned int* T1f  = (unsigned int*)alloc((size_t)Nn * WROWU * 4);
  unsigned int* T1b  = (unsigned int*)alloc((size_t)Nn * WROWU * 4);
  unsigned int* T2f  = (unsigned int*)alloc((size_t)Nn * WROWU * 4);
  unsigned int* T2b  = (unsigned int*)alloc((size_t)Nn * WROWU * 4);
  unsigned int* rh0  = (unsigned int*)alloc((size_t)Nn * RHU * 4);
  unsigned int* rh1f = (unsigned int*)alloc((size_t)Nn * RHU * 4);
  unsigned int* rh1b = (unsigned int*)alloc((size_t)Nn * RHU * 4);
  unsigned int* Ubuf = (unsigned int*)alloc((size_t)Nn * RHU * 4);
  // conv2 overlap buffers (tier 1)
  unsigned int* rh2fN = (unsigned int*)alloc((size_t)Nn * RHU * 4);
  unsigned int* rh2bN = (unsigned int*)alloc((size_t)Nn * RHU * 4);
  size_t off1 = off;
  // conv1 passA partial (tier 2): 160000 x 128 f32 = 81.92 MB
  float* Pbuf = (float*)alloc((size_t)MROWS * 128 * sizeof(float));
  size_t off2 = off;
  bool ws1 = (off1 <= ws_size);
  bool ws2 = (off2 <= ws_size);

  hipMemsetAsync(ws, 0, 4 * 40960, stream);
  detect_idx<<<1, 64, 0, stream>>>(idx, flag);
  deg_x0_wt<<<GDEG + GX0 + 240, 256, 0, stream>>>(
      idx, ew, deg_f, deg_b, cnt_f, cnt_b, flag,
      x, h, A0, ru_param, c_param, Wt1, Wt2);
  exscan_two<<<2, 256, 0, stream>>>(cnt_f, cnt_b, rp_f, rp_b, cur_f, cur_b, Nn);
  fill_csr<<<En / 256, 256, 0, stream>>>(idx, ew, deg_f, deg_b, cur_f, cur_b,
                                         cwf, cwb, flag);

  const int gP = (Nn / 4) * 8;   // 4 rows/block (1 per wave) x 8 XCD slices

  // ===== conv1 diffusion =====
  prop_dualX<192, 24, 2><<<gP, 256, 0, stream>>>(
      (const uint4v*)A0, (uint4v*)T1f, (uint4v*)T1b, rp_f, cwf, rp_b, cwb);

  Msrc g1;
  g1.xs[0] = (const uint4*)A0;  g1.rh[0] = nullptr;
  g1.xs[1] = (const uint4*)T1f; g1.rh[1] = nullptr;
  g1.xs[2] = (const uint4*)T1b; g1.rh[2] = nullptr;
  g1.xs[3] = (const uint4*)T2f; g1.rh[3] = nullptr;
  g1.xs[4] = (const uint4*)T2b; g1.rh[4] = nullptr;

  if (ws2) {
    // passA (terms 0-2 -> Pbuf) overlapped with both second-order propagations
    Msrc g1a = g1;               // only first 3 terms used
    fused_g1a<<<41256, 256, 0, stream>>>(
        g1a, Wt1, Pbuf,
        (const uint4v*)T1f, (uint4v*)T2f, rp_f, cwf,
        (const uint4v*)T1b, (uint4v*)T2b, rp_b, cwb);
    // passB: terms 3,4 (t0=3) + partial -> sigmoid epilogue
    Msrc g1b;
    g1b.xs[0] = (const uint4*)T2f; g1b.rh[0] = nullptr;
    g1b.xs[1] = (const uint4*)T2b; g1b.rh[1] = nullptr;
    g1b.xs[2] = nullptr; g1b.rh[2] = nullptr;
    g1b.xs[3] = nullptr; g1b.rh[3] = nullptr;
    g1b.xs[4] = nullptr; g1b.rh[4] = nullptr;
    gemm_mfma<128, 4><<<MROWS / 128, 256, 0, stream>>>(
        g1b, 2, 3, Wt1, ru_bias, nullptr,
        (unsigned short*)rh0, (unsigned short*)Ubuf, nullptr, h, Pbuf);
  } else {
    prop_ckX<192, 24, 2><<<gP, 256, 0, stream>>>(
        (const uint4v*)T1f, (uint4v*)T2f, rp_f, cwf, 2.f);
    prop_ckX<192, 24, 2><<<gP, 256, 0, stream>>>(
        (const uint4v*)T1b, (uint4v*)T2b, rp_b, cwb, 2.f);
    gemm_mfma<128, 0><<<MROWS / 128, 256, 0, stream>>>(
        g1, 5, 0, Wt1, ru_bias, nullptr,
        (unsigned short*)rh0, (unsigned short*)Ubuf, nullptr, h, nullptr);
  }

  // ===== conv2 diffusion on rh =====
  prop_dualX<128, 16, 4><<<gP, 256, 0, stream>>>(
      (const uint4v*)rh0, (uint4v*)rh1f, (uint4v*)rh1b, rp_f, cwf, rp_b, cwb);

  // conv2 pass A (terms 0,1,2) overlapped with the rh second-order propagations
  Msrc g2a;
  g2a.xs[0] = (const uint4*)A0;  g2a.rh[0] = (const uint4*)rh0;
  g2a.xs[1] = (const uint4*)T1f; g2a.rh[1] = (const uint4*)rh1f;
  g2a.xs[2] = (const uint4*)T1b; g2a.rh[2] = (const uint4*)rh1b;
  g2a.xs[3] = nullptr; g2a.rh[3] = nullptr;
  g2a.xs[4] = nullptr; g2a.rh[4] = nullptr;

  const uint4* g2b_rh0;
  const uint4* g2b_rh1;
  if (ws1) {
    fused_g2a<<<41256, 256, 0, stream>>>(
        g2a, Wt2, c_bias, outp,
        (const uint4v*)rh1f, (uint4v*)rh2fN, rp_f, cwf,
        (const uint4v*)rh1b, (uint4v*)rh2bN, rp_b, cwb);
    g2b_rh0 = (const uint4*)rh2fN;
    g2b_rh1 = (const uint4*)rh2bN;
  } else {
    gemm_mfma<64, 1><<<MROWS / 128, 256, 0, stream>>>(
        g2a, 3, 0, Wt2, c_bias, outp, nullptr, nullptr, nullptr, nullptr, nullptr);
    prop_ckX<128, 16, 4><<<gP, 256, 0, stream>>>(
        (const uint4v*)rh1f, (uint4v*)rh0, rp_f, cwf, 2.f);   // rh2f -> rh0
    prop_ckX<128, 16, 4><<<gP, 256, 0, stream>>>(
        (const uint4v*)rh1b, (uint4v*)rh1f, rp_b, cwb, 2.f);  // rh2b -> rh1f
    g2b_rh0 = (const uint4*)rh0;
    g2b_rh1 = (const uint4*)rh1f;
  }

  // conv2 pass B: terms 3,4 (weight base t0=3) + fused GRU final
  Msrc g2b;
  g2b.xs[0] = (const uint4*)T2f; g2b.rh[0] = g2b_rh0;
  g2b.xs[1] = (const uint4*)T2b; g2b.rh[1] = g2b_rh1;
  g2b.xs[2] = nullptr; g2b.rh[2] = nullptr;
  g2b.xs[3] = nullptr; g2b.rh[3] = nullptr;
  g2b.xs[4] = nullptr; g2b.rh[4] = nullptr;
  gemm_mfma<64, 2><<<MROWS / 128, 256, 0, stream>>>(
      g2b, 2, 3, Wt2, c_bias, outp, nullptr, nullptr,
      (const unsigned short*)Ubuf, h, nullptr);
}